// Round 7
// baseline (393.358 us; speedup 1.0000x reference)
//
#include <hip/hip_runtime.h>

// CrossEmbed2GraphByProduct: B=512, R=264, K=32, S=9
// out = [ intra (B*R*R) | inter (B*S*S) | adjacency (B*R*R) ]  (fp32)
//
// adj_intra_mfma: ONE block per batch (512 blocks, 8 waves). Stage E[b] as
//   bf16 in LDS once; wave owns a tile-row (A-fragment hoisted), sweeps 17
//   col-tiles with one mfma_f32_16x16x32_bf16 each. Hot path (tr<16, tc<16)
//   is bounds-check-free; edge tiles specialized. Plain dword stores (L2
//   write-combines the 4x64B row segments; consecutive tc keeps them local).
// inter_k: inter[b,s,t] = dot(segsum_s, segsum_t)/(|s||t|)  (block mean of
//   gram == gram of segment sums). Tiny.

constexpr int B_ = 512, R_ = 264, K_ = 32, S_ = 9;
constexpr int LDR_ = 40;  // LDS row stride in bf16 units (80 B)
constexpr long long NI_ = (long long)B_ * R_ * R_;  // 35,684,352
constexpr long long NS_ = (long long)B_ * S_ * S_;  //     41,472

typedef float f32x4 __attribute__((ext_vector_type(4)));
typedef short bf16x8 __attribute__((ext_vector_type(8)));

static __device__ inline unsigned short f2bf(float f) {  // RNE fp32->bf16
  unsigned int u = __builtin_bit_cast(unsigned int, f);
  u += 0x7fffu + ((u >> 16) & 1u);
  return (unsigned short)(u >> 16);
}

__global__ __launch_bounds__(512, 8) void adj_intra_mfma(
    const float* __restrict__ emb, float* __restrict__ out) {
  __shared__ unsigned short Ebf[272 * LDR_];  // 21,760 B
  __shared__ unsigned char seg_lut[272];

  const int b = blockIdx.x;
  const int tid = threadIdx.x;
  const float* __restrict__ eb = emb + (size_t)b * R_ * K_;

  // ---- stage: E[b] (264x32 fp32) -> bf16 LDS [row][k], coalesced float4
  for (int idx = tid; idx < (R_ * K_) / 4; idx += 512) {  // 2112 float4s
    const int r = idx >> 3;
    const int k4 = (idx & 7) * 4;
    const f32x4 v = *reinterpret_cast<const f32x4*>(eb + r * K_ + k4);
    uint2 pk;
    pk.x = (unsigned int)f2bf(v.x) | ((unsigned int)f2bf(v.y) << 16);
    pk.y = (unsigned int)f2bf(v.z) | ((unsigned int)f2bf(v.w) << 16);
    *reinterpret_cast<uint2*>(&Ebf[r * LDR_ + k4]) = pk;  // ds_write_b64
  }
  if (tid < 8 * LDR_) Ebf[264 * LDR_ + tid] = 0;  // zero pad rows 264..271
  if (tid < 272) {
    const int x = tid;
    seg_lut[x] = (x >= 28) + (x >= 58) + (x >= 92) + (x >= 121) +
                 (x >= 150) + (x >= 180) + (x >= 210) + (x >= 240);
  }
  __syncthreads();

  const int wave = tid >> 6, lane = tid & 63;
  const int half = lane >> 4;   // k-slice (input) / row-quad (output)
  const int l15 = lane & 15;    // entity (input) / col (output)

  float* __restrict__ intra_out = out;
  float* __restrict__ adj_out = out + NI_ + NS_;
  const size_t bbase = (size_t)b * ((long long)R_ * R_);

  // per-lane B-side column index & segment (same for every tile-row)
  // A-side row segment ids per (half,q) are computed per tile-row below.

  // ---- rows 0..15: wave handles tile-rows {wave, wave+8}, all checks free
#pragma unroll
  for (int rr = 0; rr < 2; ++rr) {
    const int tr = wave + rr * 8;
    const bf16x8 af = *reinterpret_cast<const bf16x8*>(
        &Ebf[(tr * 16 + l15) * LDR_ + half * 8]);
    const int ibase = tr * 16 + half * 4;
    const int si0 = seg_lut[ibase + 0], si1 = seg_lut[ibase + 1];
    const int si2 = seg_lut[ibase + 2], si3 = seg_lut[ibase + 3];
    float* __restrict__ adj_row = adj_out + bbase + (size_t)ibase * R_;
    float* __restrict__ intra_row = intra_out + bbase + (size_t)ibase * R_;

    for (int tc = 0; tc < 17; ++tc) {
      const bf16x8 bfr = *reinterpret_cast<const bf16x8*>(
          &Ebf[(tc * 16 + l15) * LDR_ + half * 8]);
      f32x4 acc = {0.f, 0.f, 0.f, 0.f};
      acc = __builtin_amdgcn_mfma_f32_16x16x32_bf16(af, bfr, acc, 0, 0, 0);
      const int j = tc * 16 + l15;
      if (j < R_) {  // only possible fail at tc==16
        const int sj = seg_lut[j];
        adj_row[(size_t)0 * R_ + j] = acc[0];
        adj_row[(size_t)1 * R_ + j] = acc[1];
        adj_row[(size_t)2 * R_ + j] = acc[2];
        adj_row[(size_t)3 * R_ + j] = acc[3];
        intra_row[(size_t)0 * R_ + j] = (si0 == sj) ? acc[0] : 0.0f;
        intra_row[(size_t)1 * R_ + j] = (si1 == sj) ? acc[1] : 0.0f;
        intra_row[(size_t)2 * R_ + j] = (si2 == sj) ? acc[2] : 0.0f;
        intra_row[(size_t)3 * R_ + j] = (si3 == sj) ? acc[3] : 0.0f;
      }
    }
  }

  // ---- tile-row 16 (rows 256..263 valid): col-tiles split across waves
  {
    const int tr = 16;
    const bf16x8 af = *reinterpret_cast<const bf16x8*>(
        &Ebf[(tr * 16 + l15) * LDR_ + half * 8]);
    const int ibase = tr * 16 + half * 4;  // 256..268
    for (int tc = wave; tc < 17; tc += 8) {
      const bf16x8 bfr = *reinterpret_cast<const bf16x8*>(
          &Ebf[(tc * 16 + l15) * LDR_ + half * 8]);
      f32x4 acc = {0.f, 0.f, 0.f, 0.f};
      acc = __builtin_amdgcn_mfma_f32_16x16x32_bf16(af, bfr, acc, 0, 0, 0);
      const int j = tc * 16 + l15;
      if (j < R_) {
        const int sj = seg_lut[j];
#pragma unroll
        for (int q = 0; q < 4; ++q) {
          const int i = ibase + q;
          if (i < R_) {
            const float v = acc[q];
            const size_t idx = bbase + (size_t)i * R_ + j;
            adj_out[idx] = v;
            intra_out[idx] = (seg_lut[i] == sj) ? v : 0.0f;
          }
        }
      }
    }
  }
}

__global__ __launch_bounds__(256) void inter_k(
    const float* __restrict__ emb, float* __restrict__ out) {
  constexpr int ENDS[S_] = {28, 58, 92, 121, 150, 180, 210, 240, 264};
  constexpr int STARTS[S_] = {0, 28, 58, 92, 121, 150, 180, 210, 240};
  constexpr float SZ[S_] = {28.f, 30.f, 34.f, 29.f, 29.f, 30.f, 30.f, 30.f, 24.f};

  __shared__ float ps[S_ * 8 * 32];   // [s][q][k] chunk partials
  __shared__ float ss[32 * 12];       // [k][s] segment sums (padded)

  const int b = blockIdx.x, tid = threadIdx.x;
  const int k = tid & 31, q = tid >> 5;  // q = 0..7
  const float* __restrict__ eb = emb + (size_t)b * R_ * K_;

#pragma unroll
  for (int s = 0; s < S_; ++s) {
    const int lo = STARTS[s], len = ENDS[s] - STARTS[s];
    const int c0 = lo + (len * q) / 8, c1 = lo + (len * (q + 1)) / 8;
    float a = 0.0f;
    for (int r = c0; r < c1; ++r) a += eb[r * K_ + k];
    ps[(s * 8 + q) * 32 + k] = a;
  }
  __syncthreads();
  for (int c = tid; c < S_ * 32; c += 256) {  // reduce 8 chunks -> ss[k][s]
    const int s = c >> 5, kk = c & 31;
    float a = 0.0f;
#pragma unroll
    for (int qq = 0; qq < 8; ++qq) a += ps[(s * 8 + qq) * 32 + kk];
    ss[kk * 12 + s] = a;
  }
  __syncthreads();
  if (tid < S_ * S_) {
    const int s = tid / S_, t = tid % S_;
    float d = 0.0f;
    for (int kk = 0; kk < 32; ++kk) d += ss[kk * 12 + s] * ss[kk * 12 + t];
    d /= (SZ[s] * SZ[t]);
    out[NI_ + (size_t)b * (S_ * S_) + tid] = d;
  }
}

extern "C" void kernel_launch(void* const* d_in, const int* in_sizes, int n_in,
                              void* d_out, int out_size, void* d_ws,
                              size_t ws_size, hipStream_t stream) {
  const float* emb = (const float*)d_in[0];
  float* out = (float*)d_out;
  hipLaunchKernelGGL(adj_intra_mfma, dim3(B_), dim3(512), 0, stream, emb, out);
  hipLaunchKernelGGL(inter_k, dim3(B_), dim3(256), 0, stream, emb, out);
}

// Round 8
// 373.465 us; speedup vs baseline: 1.0533x; 1.0533x over previous
//
#include <hip/hip_runtime.h>

// CrossEmbed2GraphByProduct: B=512, R=264, K=32, S=9
// out = [ intra (B*R*R) | inter (B*S*S) | adjacency (B*R*R) ]  (fp32)
//
// adj_intra_mfma: grid (512 batches, 2 stripes) = 1024 blocks, 8 waves each
//   -> exactly 4 blocks/CU * 8 waves = 32 waves/CU (full occupancy; R7 showed
//   halving this costs ~40 us). Stage E[b] as bf16 in LDS (2x redundant; 34 MB
//   extra fetch ~= 7 us of BW, cheap). Work = 34 jobs (tile-row, col-half);
//   stripe owns 17, wave strides by 8. Per job: A-fragment hoisted, sweep
//   consecutive col-tiles with one mfma_f32_16x16x32_bf16 each; stores hit
//   adjacent 64B segments of the same 4-row band (L2 write-combining).
// inter_k: inter[b,s,t] = dot(segsum_s, segsum_t)/(|s||t|)  (block mean of
//   gram == gram of segment sums). Tiny.

constexpr int B_ = 512, R_ = 264, K_ = 32, S_ = 9;
constexpr int LDR_ = 40;  // LDS row stride in bf16 units (80 B)
constexpr long long NI_ = (long long)B_ * R_ * R_;  // 35,684,352
constexpr long long NS_ = (long long)B_ * S_ * S_;  //     41,472

typedef float f32x4 __attribute__((ext_vector_type(4)));
typedef short bf16x8 __attribute__((ext_vector_type(8)));

static __device__ inline unsigned short f2bf(float f) {  // RNE fp32->bf16
  unsigned int u = __builtin_bit_cast(unsigned int, f);
  u += 0x7fffu + ((u >> 16) & 1u);
  return (unsigned short)(u >> 16);
}

__global__ __launch_bounds__(512, 8) void adj_intra_mfma(
    const float* __restrict__ emb, float* __restrict__ out) {
  __shared__ unsigned short Ebf[272 * LDR_];  // 21,760 B
  __shared__ unsigned char seg_lut[272];

  const int b = blockIdx.x;
  const int stripe = blockIdx.y;  // 0,1
  const int tid = threadIdx.x;
  const float* __restrict__ eb = emb + (size_t)b * R_ * K_;

  // ---- stage: E[b] (264x32 fp32) -> bf16 LDS [row][k], coalesced float4
  for (int idx = tid; idx < (R_ * K_) / 4; idx += 512) {  // 2112 float4s
    const int r = idx >> 3;
    const int k4 = (idx & 7) * 4;
    const f32x4 v = *reinterpret_cast<const f32x4*>(eb + r * K_ + k4);
    uint2 pk;
    pk.x = (unsigned int)f2bf(v.x) | ((unsigned int)f2bf(v.y) << 16);
    pk.y = (unsigned int)f2bf(v.z) | ((unsigned int)f2bf(v.w) << 16);
    *reinterpret_cast<uint2*>(&Ebf[r * LDR_ + k4]) = pk;  // ds_write_b64
  }
  if (tid < 8 * LDR_) Ebf[264 * LDR_ + tid] = 0;  // zero pad rows 264..271
  if (tid < 272) {
    const int x = tid;
    seg_lut[x] = (x >= 28) + (x >= 58) + (x >= 92) + (x >= 121) +
                 (x >= 150) + (x >= 180) + (x >= 210) + (x >= 240);
  }
  __syncthreads();

  const int wave = tid >> 6, lane = tid & 63;
  const int half = lane >> 4;   // k-slice (input) / row-quad (output)
  const int l15 = lane & 15;    // entity (input) / col (output)

  float* __restrict__ intra_out = out;
  float* __restrict__ adj_out = out + NI_ + NS_;
  const size_t bbase = (size_t)b * ((long long)R_ * R_);

  // jobs: j in [stripe*17, stripe*17+17), tr = j/2 (0..16), col-half = j&1
  for (int j = stripe * 17 + wave; j < stripe * 17 + 17; j += 8) {
    const int tr = j >> 1;
    const int th = j & 1;
    const bf16x8 af = *reinterpret_cast<const bf16x8*>(
        &Ebf[(tr * 16 + l15) * LDR_ + half * 8]);
    const int ibase = tr * 16 + half * 4;
    const bool rowok = (ibase + 3) < R_;  // false only for tr==16, half>=2
    const int si0 = seg_lut[ibase + 0], si1 = seg_lut[ibase + 1];
    const int si2 = seg_lut[ibase + 2], si3 = seg_lut[ibase + 3];
    float* __restrict__ adj_row = adj_out + bbase + (size_t)ibase * R_;
    float* __restrict__ intra_row = intra_out + bbase + (size_t)ibase * R_;

    const int tc_lo = th ? 9 : 0;
    const int tc_hi = th ? 17 : 9;
    for (int tc = tc_lo; tc < tc_hi; ++tc) {
      const bf16x8 bfr = *reinterpret_cast<const bf16x8*>(
          &Ebf[(tc * 16 + l15) * LDR_ + half * 8]);
      f32x4 acc = {0.f, 0.f, 0.f, 0.f};
      acc = __builtin_amdgcn_mfma_f32_16x16x32_bf16(af, bfr, acc, 0, 0, 0);
      const int col = tc * 16 + l15;
      if (rowok && col < R_) {  // col check can only fail at tc==16
        const int sj = seg_lut[col];
        adj_row[(size_t)0 * R_ + col] = acc[0];
        adj_row[(size_t)1 * R_ + col] = acc[1];
        adj_row[(size_t)2 * R_ + col] = acc[2];
        adj_row[(size_t)3 * R_ + col] = acc[3];
        intra_row[(size_t)0 * R_ + col] = (si0 == sj) ? acc[0] : 0.0f;
        intra_row[(size_t)1 * R_ + col] = (si1 == sj) ? acc[1] : 0.0f;
        intra_row[(size_t)2 * R_ + col] = (si2 == sj) ? acc[2] : 0.0f;
        intra_row[(size_t)3 * R_ + col] = (si3 == sj) ? acc[3] : 0.0f;
      }
    }
  }
}

__global__ __launch_bounds__(256) void inter_k(
    const float* __restrict__ emb, float* __restrict__ out) {
  constexpr int ENDS[S_] = {28, 58, 92, 121, 150, 180, 210, 240, 264};
  constexpr int STARTS[S_] = {0, 28, 58, 92, 121, 150, 180, 210, 240};
  constexpr float SZ[S_] = {28.f, 30.f, 34.f, 29.f, 29.f, 30.f, 30.f, 30.f, 24.f};

  __shared__ float ps[S_ * 8 * 32];   // [s][q][k] chunk partials
  __shared__ float ss[32 * 12];       // [k][s] segment sums (padded)

  const int b = blockIdx.x, tid = threadIdx.x;
  const int k = tid & 31, q = tid >> 5;  // q = 0..7
  const float* __restrict__ eb = emb + (size_t)b * R_ * K_;

#pragma unroll
  for (int s = 0; s < S_; ++s) {
    const int lo = STARTS[s], len = ENDS[s] - STARTS[s];
    const int c0 = lo + (len * q) / 8, c1 = lo + (len * (q + 1)) / 8;
    float a = 0.0f;
    for (int r = c0; r < c1; ++r) a += eb[r * K_ + k];
    ps[(s * 8 + q) * 32 + k] = a;
  }
  __syncthreads();
  for (int c = tid; c < S_ * 32; c += 256) {  // reduce 8 chunks -> ss[k][s]
    const int s = c >> 5, kk = c & 31;
    float a = 0.0f;
#pragma unroll
    for (int qq = 0; qq < 8; ++qq) a += ps[(s * 8 + qq) * 32 + kk];
    ss[kk * 12 + s] = a;
  }
  __syncthreads();
  if (tid < S_ * S_) {
    const int s = tid / S_, t = tid % S_;
    float d = 0.0f;
    for (int kk = 0; kk < 32; ++kk) d += ss[kk * 12 + s] * ss[kk * 12 + t];
    d /= (SZ[s] * SZ[t]);
    out[NI_ + (size_t)b * (S_ * S_) + tid] = d;
  }
}

extern "C" void kernel_launch(void* const* d_in, const int* in_sizes, int n_in,
                              void* d_out, int out_size, void* d_ws,
                              size_t ws_size, hipStream_t stream) {
  const float* emb = (const float*)d_in[0];
  float* out = (float*)d_out;
  hipLaunchKernelGGL(adj_intra_mfma, dim3(B_, 2), dim3(512), 0, stream, emb, out);
  hipLaunchKernelGGL(inter_k, dim3(B_), dim3(256), 0, stream, emb, out);
}